// Round 3
// baseline (56143.079 us; speedup 1.0000x reference)
//
#include <hip/hip_runtime.h>
#include <math.h>

// Problem constants (match reference)
constexpr int B_   = 64;
constexpr int T_   = 200;
constexpr int L_IN = 100;
constexpr int S_   = 8;
constexpr int XC_  = 16;
constexpr int H_   = 256;
constexpr int W_   = 128;
constexpr int O_   = 8;
constexpr int GR_  = 3 * H_;      // 768
constexpr int HXC  = H_ * XC_;    // 4096

constexpr int NB    = 4;          // blocks per batch
constexpr int ZPB   = H_ / NB;    // 64 z-rows per block
constexpr int RPB   = HXC / NB;   // 1024 W2-rows per block
constexpr int W2REG = 48;         // W2 k-planes held in registers per thread

#define NT 1024

// Workspace layout (floats)
constexpr size_t OFF_WIHT = 0;                              // [24][768]
constexpr size_t OFF_WHHT = OFF_WIHT + 24ull * GR_;         // [256][768]
constexpr size_t OFF_W0T  = OFF_WHHT + (size_t)H_ * GR_;    // [256][128]
constexpr size_t OFF_W1T  = OFF_W0T + (size_t)H_ * W_;      // [128][128]
constexpr size_t OFF_W2T  = OFF_W1T + (size_t)W_ * W_;      // [128][4096]
constexpr size_t OFF_KX   = OFF_W2T + (size_t)W_ * HXC;     // [64][2][4][64]
constexpr size_t OFF_SEQ  = OFF_KX + (size_t)B_ * 2 * NB * ZPB; // [64][4][16] uint
constexpr size_t WS_FLOATS = OFF_SEQ + (size_t)B_ * NB * 16;    // ~3.15 MB

// Transpose: in is R x K row-major; out[k*R + j] = in[j*K + k]
__global__ void transpose_kernel(const float* __restrict__ in, float* __restrict__ out,
                                 int R, int K) {
    int o = blockIdx.x * blockDim.x + threadIdx.x;
    if (o < R * K) {
        int k = o / R;
        int j = o - k * R;
        out[o] = in[j * K + k];
    }
}

__global__ void init_seq_kernel(unsigned* __restrict__ seq, int n) {
    int i = blockIdx.x * blockDim.x + threadIdx.x;
    if (i < n) seq[i] = 0u;
}

__device__ __forceinline__ float softplus_f(float x) {
    return fmaxf(x, 0.f) + log1pf(expf(-fabsf(x)));
}
__device__ __forceinline__ float sigmoid_f(float x) {
    return 1.f / (1.f + expf(-x));
}

// ---------------------------------------------------------------------------
// Distributed kernel: 4 blocks per batch, k/z-quarter exchange through global
// memory with agent-scope atomics. 256 blocks == 256 CUs (co-resident).
// ---------------------------------------------------------------------------
__global__ __launch_bounds__(NT, 4) void gru_cde_dist(
    const float* __restrict__ y_past,   // [B][L_IN][S]
    const float* __restrict__ tvals,    // [T]
    const float* __restrict__ cx,       // [B][T][XC-1]
    const float* __restrict__ wihT,     // [24][768]
    const float* __restrict__ whhT,     // [256][768]
    const float* __restrict__ gru_b,    // [768]
    const float* __restrict__ gru_bn,   // [256]
    const float* __restrict__ w0T,      // [256][128]
    const float* __restrict__ b0,       // [128]
    const float* __restrict__ w1T,      // [128][128]
    const float* __restrict__ b1,       // [128]
    const float* __restrict__ w2T,      // [128][4096]
    const float* __restrict__ b2,       // [4096]
    const float* __restrict__ ro_w,     // [8][256]
    const float* __restrict__ ro_b,     // [8]
    float* __restrict__ kx,             // [64][2][4][64] exchange data
    unsigned* __restrict__ seq,         // [64][4][16] sequence flags
    float* __restrict__ out)            // [B][100][8]
{
    const int b   = blockIdx.x & (B_ - 1);   // batch; blocks b,b+64,b+128,b+192
    const int q   = blockIdx.x >> 6;         // quarter 0..3 (same XCD per batch)
    const int tid = threadIdx.x;

    __shared__ __align__(16) float z[H_];
    __shared__ __align__(16) float zs[H_];
    __shared__ __align__(16) float kb[6][H_];
    __shared__ __align__(16) float a0s[W_];
    __shared__ __align__(16) float a1s[W_];
    __shared__ float red[8][W_];
    __shared__ float gsum[192];
    __shared__ float gaux[ZPB];
    __shared__ float xb[S_ + XC_];
    __shared__ float dxs[XC_];

    int  epoch = 0;
    bool dead  = false;   // sticky hang-guard (thread 0 only)

    // Owner threads write v to LDS dst row + global exchange slot.
    auto publish = [&](float v, int il, float* dst) {
        dst[q * ZPB + il] = v;
        __hip_atomic_store(&kx[(((size_t)b * 2 + (epoch & 1)) * NB + q) * ZPB + il], v,
                           __ATOMIC_RELAXED, __HIP_MEMORY_SCOPE_AGENT);
    };

    // Barrier among the 4 blocks of this batch, then gather peers' rows into dst.
    auto exchange = [&](float* dst) {
        __syncthreads();   // drains vmcnt: kx stores complete at coherence point
        if (tid == 0) {
            __threadfence();
            __hip_atomic_store(&seq[(b * NB + q) * 16], (unsigned)epoch,
                               __ATOMIC_RELEASE, __HIP_MEMORY_SCOPE_AGENT);
            for (int qq = 0; qq < NB; ++qq) {
                if (qq == q || dead) continue;
                unsigned* sp = &seq[(b * NB + qq) * 16];
                int guard = 0;
                while (__hip_atomic_load(sp, __ATOMIC_ACQUIRE,
                                         __HIP_MEMORY_SCOPE_AGENT) < (unsigned)epoch) {
                    __builtin_amdgcn_s_sleep(1);
                    if (++guard > (1 << 22)) { dead = true; break; }
                }
            }
        }
        __syncthreads();
        if (tid < H_) {
            int qq = tid >> 6, ii = tid & 63;
            if (qq != q)
                dst[qq * ZPB + ii] = __hip_atomic_load(
                    &kx[(((size_t)b * 2 + (epoch & 1)) * NB + qq) * ZPB + ii],
                    __ATOMIC_RELAXED, __HIP_MEMORY_SCOPE_AGENT);
        }
        __syncthreads();
    };

    // ---------------- Encoder: 100 GRU steps, gate rows distributed ----------
    // Block q owns z-rows [q*64, (q+1)*64): gate rows q*64+l, 256+q*64+l, 512+q*64+l
    const int   seg = tid >> 6;          // 0=reset,1=update,2=new (tid<192)
    const int   l63 = tid & 63;
    const int   gr  = seg * H_ + q * ZPB + l63;
    const float gbr = (tid < 192) ? gru_b[gr] : 0.f;
    const float bnr = (tid < ZPB) ? gru_bn[q * ZPB + tid] : 0.f;

    if (tid < H_) z[tid] = 0.f;
    __syncthreads();

    for (int step = 0; step < L_IN; ++step) {
        if (tid < S_ + XC_) {
            float v;
            if (tid < S_)                v = y_past[(b * L_IN + step) * S_ + tid];
            else if (tid < S_ + XC_ - 1) v = cx[(b * T_ + step) * (XC_ - 1) + (tid - S_)];
            else                         v = tvals[step];
            xb[tid] = v;
        }
        __syncthreads();
        if (tid < 192) {
            float ig = gbr;
            #pragma unroll
            for (int k = 0; k < S_ + XC_; ++k) ig += wihT[k * GR_ + gr] * xb[k];
            float hg = 0.f, hg2 = 0.f;
            #pragma unroll 8
            for (int k = 0; k < H_; k += 2) {
                hg  += whhT[k * GR_ + gr]       * z[k];
                hg2 += whhT[(k + 1) * GR_ + gr] * z[k + 1];
            }
            hg += hg2;
            if (seg < 2) gsum[tid] = ig + hg;
            else { gsum[tid] = ig; gaux[l63] = hg; }
        }
        __syncthreads();
        epoch++;
        if (tid < ZPB) {
            float rr = sigmoid_f(gsum[tid]);
            float uu = sigmoid_f(gsum[64 + tid]);
            float nn = tanhf(gsum[128 + tid] + rr * (gaux[tid] + bnr));
            float zo = z[q * ZPB + tid];
            publish(nn + uu * (zo - nn), tid, z);
        }
        exchange(z);
    }

    // readout (block q==0 only): out[b][idx][:] = ro_w @ z + ro_b
    auto readout = [&](int idx) {
        if (q == 0 && tid < 8 * 64) {
            int o  = tid >> 6;
            int kk = tid & 63;
            float4 wv = reinterpret_cast<const float4*>(ro_w)[o * 64 + kk];
            float4 zv = *reinterpret_cast<const float4*>(&z[kk * 4]);
            float p = wv.x * zv.x + wv.y * zv.y + wv.z * zv.z + wv.w * zv.w;
            p += __shfl_xor(p, 1);
            p += __shfl_xor(p, 2);
            p += __shfl_xor(p, 4);
            p += __shfl_xor(p, 8);
            p += __shfl_xor(p, 16);
            p += __shfl_xor(p, 32);
            if (kk == 0) out[(b * L_IN + idx) * O_ + o] = p + ro_b[o];
        }
    };

    readout(0);

    // ---------------- Register-resident weights for the ODE phase ------------
    const int r = tid & 127;       // MLP output row
    const int g = tid >> 7;        // split-K group 0..7
    const int jrow = q * RPB + tid; // owned W2 row
    float w2r[W2REG];
    #pragma unroll
    for (int k = 0; k < W2REG; ++k) w2r[k] = w2T[(size_t)k * HXC + jrow];
    float w0r[32];
    #pragma unroll
    for (int i = 0; i < 32; ++i) w0r[i] = w0T[(size_t)(g * 32 + i) * W_ + r];
    float w1r[16];
    #pragma unroll
    for (int i = 0; i < 16; ++i) w1r[i] = w1T[(size_t)(g * 16 + i) * W_ + r];
    const float b2j = b2[jrow];
    const float b0r = (tid < W_) ? b0[tid] : 0.f;
    const float b1r = (tid < W_) ? b1[tid] : 0.f;
    float dxr = 0.f;

    // vf: kb[s] = vf(zin, dxdt); block computes full a0/a1 (replicated), own W2 rows
    auto vf = [&](const float* zin, int s) {
        {   // a0 partial: row r, k in [g*32, g*32+32)
            const float4* z4 = reinterpret_cast<const float4*>(zin) + g * 8;
            float acc0 = 0.f, acc1 = 0.f;
            #pragma unroll
            for (int c = 0; c < 8; ++c) {
                float4 zv = z4[c];
                acc0 += w0r[c * 4 + 0] * zv.x + w0r[c * 4 + 1] * zv.y;
                acc1 += w0r[c * 4 + 2] * zv.z + w0r[c * 4 + 3] * zv.w;
            }
            red[g][r] = acc0 + acc1;
        }
        __syncthreads();
        if (tid < W_) {
            float sa = b0r;
            #pragma unroll
            for (int gg = 0; gg < 8; ++gg) sa += red[gg][tid];
            a0s[tid] = softplus_f(sa);
        }
        __syncthreads();
        {   // a1 partial: row r, k in [g*16, g*16+16)
            const float4* a4 = reinterpret_cast<const float4*>(a0s) + g * 4;
            float acc0 = 0.f, acc1 = 0.f;
            #pragma unroll
            for (int c = 0; c < 4; ++c) {
                float4 av = a4[c];
                acc0 += w1r[c * 4 + 0] * av.x + w1r[c * 4 + 1] * av.y;
                acc1 += w1r[c * 4 + 2] * av.z + w1r[c * 4 + 3] * av.w;
            }
            red[g][r] = acc0 + acc1;
        }
        __syncthreads();
        if (tid < W_) {
            float sa = b1r;
            #pragma unroll
            for (int gg = 0; gg < 8; ++gg) sa += red[gg][tid];
            a1s[tid] = softplus_f(sa);
        }
        __syncthreads();
        // W2 row jrow: register part (k<W2REG) + L2-streamed part
        float acc0 = 0.f, acc1 = 0.f, acc2 = 0.f, acc3 = 0.f;
        {
            const float4* a4 = reinterpret_cast<const float4*>(a1s);
            #pragma unroll
            for (int c = 0; c < W2REG / 4; ++c) {
                float4 av = a4[c];
                acc0 += w2r[c * 4 + 0] * av.x; acc1 += w2r[c * 4 + 1] * av.y;
                acc2 += w2r[c * 4 + 2] * av.z; acc3 += w2r[c * 4 + 3] * av.w;
            }
            const float* wp = w2T + (size_t)W2REG * HXC + jrow;
            #pragma unroll 8
            for (int k = W2REG; k < W_; k += 2) {
                acc0 += wp[0]   * a1s[k];
                acc1 += wp[HXC] * a1s[k + 1];
                wp += 2 * HXC;
            }
        }
        float p = tanhf((acc0 + acc2) + (acc1 + acc3) + b2j) * dxr;
        p += __shfl_xor(p, 1);
        p += __shfl_xor(p, 2);
        p += __shfl_xor(p, 4);
        p += __shfl_xor(p, 8);
        epoch++;
        if ((tid & 15) == 0) publish(p, tid >> 4, &kb[s][0]);
        exchange(&kb[s][0]);
    };

    // ---------------- ODE: 99 intervals x 2 dopri5 substeps ------------------
    for (int i = 0; i < T_ - L_IN - 1; ++i) {
        float dt = tvals[L_IN + i + 1] - tvals[L_IN + i];
        if (tid < XC_) {
            float xa, xbv;
            if (tid < XC_ - 1) {
                xa  = cx[(b * T_ + L_IN + i) * (XC_ - 1) + tid];
                xbv = cx[(b * T_ + L_IN + i + 1) * (XC_ - 1) + tid];
            } else {
                xa  = tvals[L_IN + i];
                xbv = tvals[L_IN + i + 1];
            }
            dxs[tid] = (xbv - xa) / dt;
        }
        const float hh = dt * 0.5f;   // N_SUB = 2
        __syncthreads();
        dxr = dxs[tid & 15];          // column of this thread's W2 row

        for (int sub = 0; sub < 2; ++sub) {
            vf(z, 0);
            if (tid < H_) zs[tid] = z[tid] + hh * (0.2f * kb[0][tid]);
            __syncthreads();
            vf(zs, 1);
            if (tid < H_) zs[tid] = z[tid] + hh * (0.075f * kb[0][tid] + 0.225f * kb[1][tid]);
            __syncthreads();
            vf(zs, 2);
            if (tid < H_) zs[tid] = z[tid] + hh * ((44.f / 45.f) * kb[0][tid]
                                                - (56.f / 15.f) * kb[1][tid]
                                                + (32.f / 9.f) * kb[2][tid]);
            __syncthreads();
            vf(zs, 3);
            if (tid < H_) zs[tid] = z[tid] + hh * ((19372.f / 6561.f) * kb[0][tid]
                                                - (25360.f / 2187.f) * kb[1][tid]
                                                + (64448.f / 6561.f) * kb[2][tid]
                                                - (212.f / 729.f) * kb[3][tid]);
            __syncthreads();
            vf(zs, 4);
            if (tid < H_) zs[tid] = z[tid] + hh * ((9017.f / 3168.f) * kb[0][tid]
                                                - (355.f / 33.f) * kb[1][tid]
                                                + (46732.f / 5247.f) * kb[2][tid]
                                                + (49.f / 176.f) * kb[3][tid]
                                                - (5103.f / 18656.f) * kb[4][tid]);
            __syncthreads();
            vf(zs, 5);
            if (tid < H_) {
                z[tid] = z[tid] + hh * ((35.f / 384.f) * kb[0][tid]
                                      + (500.f / 1113.f) * kb[2][tid]
                                      + (125.f / 192.f) * kb[3][tid]
                                      - (2187.f / 6784.f) * kb[4][tid]
                                      + (11.f / 84.f) * kb[5][tid]);
            }
            __syncthreads();
        }
        readout(i + 1);
    }
}

// ---------------------------------------------------------------------------
// Fallback (ws too small): R2 monolithic kernel, original weight layouts.
// ---------------------------------------------------------------------------
template <bool TR>
__global__ __launch_bounds__(NT) void gru_cde_mono(
    const float* __restrict__ y_past, const float* __restrict__ tvals,
    const float* __restrict__ cx,
    const float* __restrict__ wih, const float* __restrict__ whh,
    const float* __restrict__ gru_b, const float* __restrict__ gru_bn,
    const float* __restrict__ w0, const float* __restrict__ b0,
    const float* __restrict__ w1, const float* __restrict__ b1,
    const float* __restrict__ w2, const float* __restrict__ b2,
    const float* __restrict__ ro_w, const float* __restrict__ ro_b,
    float* __restrict__ out)
{
    const int b   = blockIdx.x;
    const int tid = threadIdx.x;

    __shared__ __align__(16) float z[H_];
    __shared__ float zs[H_];
    __shared__ float kb[6][H_];
    __shared__ float a0s[W_];
    __shared__ float a1s[W_];
    __shared__ float red[8][W_];
    __shared__ float gsum[GR_];
    __shared__ float gaux[H_];
    __shared__ float xb[S_ + XC_];
    __shared__ float dxs[XC_];

    const float gb_t = (tid < GR_) ? gru_b[tid] : 0.f;
    const float bn_t = (tid < H_) ? gru_bn[tid] : 0.f;
    const float4 bb = reinterpret_cast<const float4*>(b2)[tid];

    if (tid < H_) z[tid] = 0.f;
    __syncthreads();

    for (int step = 0; step < L_IN; ++step) {
        if (tid < S_ + XC_) {
            float v;
            if (tid < S_)                v = y_past[(b * L_IN + step) * S_ + tid];
            else if (tid < S_ + XC_ - 1) v = cx[(b * T_ + step) * (XC_ - 1) + (tid - S_)];
            else                         v = tvals[step];
            xb[tid] = v;
        }
        __syncthreads();
        if (tid < GR_) {
            float ig = gb_t;
            #pragma unroll
            for (int k = 0; k < S_ + XC_; ++k) {
                float wv = TR ? wih[k * GR_ + tid] : wih[tid * (S_ + XC_) + k];
                ig += wv * xb[k];
            }
            float hg = 0.f;
            #pragma unroll 8
            for (int k = 0; k < H_; ++k) {
                float wv = TR ? whh[k * GR_ + tid] : whh[tid * H_ + k];
                hg += wv * z[k];
            }
            if (tid < 2 * H_) gsum[tid] = ig + hg;
            else { gsum[tid] = ig; gaux[tid - 2 * H_] = hg; }
        }
        __syncthreads();
        if (tid < H_) {
            float r = sigmoid_f(gsum[tid]);
            float u = sigmoid_f(gsum[tid + H_]);
            float n = tanhf(gsum[tid + 2 * H_] + r * (gaux[tid] + bn_t));
            z[tid] = n + u * (z[tid] - n);
        }
        __syncthreads();
    }

    auto readout = [&](int idx) {
        if (tid < 8 * 64) {
            int o  = tid >> 6;
            int kk = tid & 63;
            float4 wv = reinterpret_cast<const float4*>(ro_w)[o * 64 + kk];
            float4 zv = *reinterpret_cast<const float4*>(&z[kk * 4]);
            float p = wv.x * zv.x + wv.y * zv.y + wv.z * zv.z + wv.w * zv.w;
            p += __shfl_xor(p, 1);
            p += __shfl_xor(p, 2);
            p += __shfl_xor(p, 4);
            p += __shfl_xor(p, 8);
            p += __shfl_xor(p, 16);
            p += __shfl_xor(p, 32);
            if (kk == 0) out[(b * L_IN + idx) * O_ + o] = p + ro_b[o];
        }
    };

    readout(0);

    const float4* __restrict__ w24 = reinterpret_cast<const float4*>(w2);

    auto vf = [&](const float* zin, int s) {
        const int g = tid >> 7;
        const int r = tid & 127;
        {
            float acc = 0.f;
            const int k0 = g * 32;
            #pragma unroll 8
            for (int k = k0; k < k0 + 32; ++k) {
                float wv = TR ? w0[k * W_ + r] : w0[r * H_ + k];
                acc += wv * zin[k];
            }
            red[g][r] = acc;
        }
        __syncthreads();
        if (tid < W_) {
            float sa = b0[tid];
            #pragma unroll
            for (int gg = 0; gg < 8; ++gg) sa += red[gg][tid];
            a0s[tid] = softplus_f(sa);
        }
        __syncthreads();
        {
            float acc = 0.f;
            const int k0 = g * 16;
            #pragma unroll
            for (int k = k0; k < k0 + 16; ++k) {
                float wv = TR ? w1[k * W_ + r] : w1[r * W_ + k];
                acc += wv * a0s[k];
            }
            red[g][r] = acc;
        }
        __syncthreads();
        if (tid < W_) {
            float sa = b1[tid];
            #pragma unroll
            for (int gg = 0; gg < 8; ++gg) sa += red[gg][tid];
            a1s[tid] = softplus_f(sa);
        }
        __syncthreads();
        {
            float4 acc = make_float4(0.f, 0.f, 0.f, 0.f);
            if constexpr (TR) {
                #pragma unroll 8
                for (int k = 0; k < W_; ++k) {
                    float4 wv = w24[k * (HXC / 4) + tid];
                    float av = a1s[k];
                    acc.x += wv.x * av; acc.y += wv.y * av;
                    acc.z += wv.z * av; acc.w += wv.w * av;
                }
            } else {
                const int jj = tid * 4;
                #pragma unroll 4
                for (int k = 0; k < W_; ++k) {
                    float av = a1s[k];
                    acc.x += w2[(jj + 0) * W_ + k] * av;
                    acc.y += w2[(jj + 1) * W_ + k] * av;
                    acc.z += w2[(jj + 2) * W_ + k] * av;
                    acc.w += w2[(jj + 3) * W_ + k] * av;
                }
            }
            const int c0 = (tid * 4) & 15;
            float p = tanhf(acc.x + bb.x) * dxs[c0]
                    + tanhf(acc.y + bb.y) * dxs[c0 + 1]
                    + tanhf(acc.z + bb.z) * dxs[c0 + 2]
                    + tanhf(acc.w + bb.w) * dxs[c0 + 3];
            p += __shfl_xor(p, 1);
            p += __shfl_xor(p, 2);
            if ((tid & 3) == 0) kb[s][tid >> 2] = p;
        }
        __syncthreads();
    };

    for (int i = 0; i < T_ - L_IN - 1; ++i) {
        float dt = tvals[L_IN + i + 1] - tvals[L_IN + i];
        if (tid < XC_) {
            float xa, xbv;
            if (tid < XC_ - 1) {
                xa  = cx[(b * T_ + L_IN + i) * (XC_ - 1) + tid];
                xbv = cx[(b * T_ + L_IN + i + 1) * (XC_ - 1) + tid];
            } else {
                xa  = tvals[L_IN + i];
                xbv = tvals[L_IN + i + 1];
            }
            dxs[tid] = (xbv - xa) / dt;
        }
        const float hh = dt * 0.5f;
        __syncthreads();

        for (int sub = 0; sub < 2; ++sub) {
            vf(z, 0);
            if (tid < H_) zs[tid] = z[tid] + hh * (0.2f * kb[0][tid]);
            __syncthreads();
            vf(zs, 1);
            if (tid < H_) zs[tid] = z[tid] + hh * (0.075f * kb[0][tid] + 0.225f * kb[1][tid]);
            __syncthreads();
            vf(zs, 2);
            if (tid < H_) zs[tid] = z[tid] + hh * ((44.f / 45.f) * kb[0][tid]
                                                - (56.f / 15.f) * kb[1][tid]
                                                + (32.f / 9.f) * kb[2][tid]);
            __syncthreads();
            vf(zs, 3);
            if (tid < H_) zs[tid] = z[tid] + hh * ((19372.f / 6561.f) * kb[0][tid]
                                                - (25360.f / 2187.f) * kb[1][tid]
                                                + (64448.f / 6561.f) * kb[2][tid]
                                                - (212.f / 729.f) * kb[3][tid]);
            __syncthreads();
            vf(zs, 4);
            if (tid < H_) zs[tid] = z[tid] + hh * ((9017.f / 3168.f) * kb[0][tid]
                                                - (355.f / 33.f) * kb[1][tid]
                                                + (46732.f / 5247.f) * kb[2][tid]
                                                + (49.f / 176.f) * kb[3][tid]
                                                - (5103.f / 18656.f) * kb[4][tid]);
            __syncthreads();
            vf(zs, 5);
            if (tid < H_) {
                z[tid] = z[tid] + hh * ((35.f / 384.f) * kb[0][tid]
                                      + (500.f / 1113.f) * kb[2][tid]
                                      + (125.f / 192.f) * kb[3][tid]
                                      - (2187.f / 6784.f) * kb[4][tid]
                                      + (11.f / 84.f) * kb[5][tid]);
            }
            __syncthreads();
        }
        readout(i + 1);
    }
}

extern "C" void kernel_launch(void* const* d_in, const int* in_sizes, int n_in,
                              void* d_out, int out_size, void* d_ws, size_t ws_size,
                              hipStream_t stream) {
    const float* y_past = (const float*)d_in[0];
    const float* tvals  = (const float*)d_in[1];
    const float* cx     = (const float*)d_in[2];
    const float* wih    = (const float*)d_in[3];
    const float* whh    = (const float*)d_in[4];
    const float* gb     = (const float*)d_in[5];
    const float* gbn    = (const float*)d_in[6];
    const float* w0     = (const float*)d_in[7];
    const float* b0     = (const float*)d_in[8];
    const float* w1     = (const float*)d_in[9];
    const float* b1     = (const float*)d_in[10];
    const float* w2     = (const float*)d_in[11];
    const float* b2     = (const float*)d_in[12];
    const float* ro_w   = (const float*)d_in[13];
    const float* ro_b   = (const float*)d_in[14];
    float* out = (float*)d_out;

    if (ws_size >= WS_FLOATS * sizeof(float)) {
        float* ws = (float*)d_ws;
        auto launchT = [&](const float* in, float* o, int R, int K) {
            int n = R * K;
            transpose_kernel<<<(n + 255) / 256, 256, 0, stream>>>(in, o, R, K);
        };
        launchT(wih, ws + OFF_WIHT, GR_, S_ + XC_);
        launchT(whh, ws + OFF_WHHT, GR_, H_);
        launchT(w0,  ws + OFF_W0T,  W_, H_);
        launchT(w1,  ws + OFF_W1T,  W_, W_);
        launchT(w2,  ws + OFF_W2T,  HXC, W_);
        int nseq = B_ * NB * 16;
        init_seq_kernel<<<(nseq + 255) / 256, 256, 0, stream>>>(
            (unsigned*)(ws + OFF_SEQ), nseq);
        gru_cde_dist<<<B_ * NB, NT, 0, stream>>>(
            y_past, tvals, cx,
            ws + OFF_WIHT, ws + OFF_WHHT, gb, gbn,
            ws + OFF_W0T, b0, ws + OFF_W1T, b1, ws + OFF_W2T, b2,
            ro_w, ro_b, ws + OFF_KX, (unsigned*)(ws + OFF_SEQ), out);
    } else {
        gru_cde_mono<false><<<B_, NT, 0, stream>>>(
            y_past, tvals, cx,
            wih, whh, gb, gbn,
            w0, b0, w1, b1, w2, b2,
            ro_w, ro_b, out);
    }
}

// Round 4
// 12556.751 us; speedup vs baseline: 4.4711x; 4.4711x over previous
//
#include <hip/hip_runtime.h>
#include <math.h>

// Problem constants (match reference)
constexpr int B_   = 64;
constexpr int T_   = 200;
constexpr int L_IN = 100;
constexpr int S_   = 8;
constexpr int XC_  = 16;
constexpr int H_   = 256;
constexpr int W_   = 128;
constexpr int O_   = 8;
constexpr int GR_  = 3 * H_;      // 768
constexpr int HXC  = H_ * XC_;    // 4096

constexpr int NB    = 4;          // blocks per batch
constexpr int ZPB   = H_ / NB;    // 64 z-rows per block
constexpr int W2REG = 8;          // register-cached W2 k-planes per thread (of its 32)

#define NT 1024

// Workspace layout (floats) — unchanged from R3 for safety (w0T/w1T slots unused now)
constexpr size_t OFF_WIHT = 0;                              // [24][768]
constexpr size_t OFF_WHHT = OFF_WIHT + 24ull * GR_;         // [256][768]
constexpr size_t OFF_W0T  = OFF_WHHT + (size_t)H_ * GR_;    // (unused)
constexpr size_t OFF_W1T  = OFF_W0T + (size_t)H_ * W_;      // (unused)
constexpr size_t OFF_W2T  = OFF_W1T + (size_t)W_ * W_;      // [128][4096]
constexpr size_t OFF_KX   = OFF_W2T + (size_t)W_ * HXC;     // [64][2][4][64]
constexpr size_t OFF_SEQ  = OFF_KX + (size_t)B_ * 2 * NB * ZPB; // [64][4][16] uint
constexpr size_t WS_FLOATS = OFF_SEQ + (size_t)B_ * NB * 16;    // ~3.15 MB

// Transpose: in is R x K row-major; out[k*R + j] = in[j*K + k]
__global__ void transpose_kernel(const float* __restrict__ in, float* __restrict__ out,
                                 int R, int K) {
    int o = blockIdx.x * blockDim.x + threadIdx.x;
    if (o < R * K) {
        int k = o / R;
        int j = o - k * R;
        out[o] = in[j * K + k];
    }
}

__global__ void init_seq_kernel(unsigned* __restrict__ seq, int n) {
    int i = blockIdx.x * blockDim.x + threadIdx.x;
    if (i < n) seq[i] = 0u;
}

__device__ __forceinline__ float softplus_f(float x) {
    return fmaxf(x, 0.f) + log1pf(expf(-fabsf(x)));
}
__device__ __forceinline__ float sigmoid_f(float x) {
    return 1.f / (1.f + expf(-x));
}

// ---------------------------------------------------------------------------
// Distributed kernel: 4 blocks per batch. Exchange uses RELAXED agent-scope
// atomics only (no acquire/release/threadfence -> no L2 invalidation).
// Ordering backbone: __syncthreads() drains vmcnt(0) before s_barrier, so
// data stores reach the coherence point before the flag store issues.
// ---------------------------------------------------------------------------
__global__ __launch_bounds__(NT, 4) void gru_cde_dist(
    const float* __restrict__ y_past,   // [B][L_IN][S]
    const float* __restrict__ tvals,    // [T]
    const float* __restrict__ cx,       // [B][T][XC-1]
    const float* __restrict__ wihT,     // [24][768]
    const float* __restrict__ whhT,     // [256][768]
    const float* __restrict__ gru_b,    // [768]
    const float* __restrict__ gru_bn,   // [256]
    const float* __restrict__ w0,       // [128][256] row-major (original)
    const float* __restrict__ b0,       // [128]
    const float* __restrict__ w1,       // [128][128] row-major (original)
    const float* __restrict__ b1,       // [128]
    const float* __restrict__ w2T,      // [128][4096] k-major
    const float* __restrict__ b2,       // [4096]
    const float* __restrict__ ro_w,     // [8][256]
    const float* __restrict__ ro_b,     // [8]
    float* __restrict__ kx,             // [64][2][4][64] exchange data
    unsigned* __restrict__ seq,         // [64][4][16] sequence flags
    float* __restrict__ out)            // [B][100][8]
{
    const int b   = blockIdx.x & (B_ - 1);   // batch
    const int q   = blockIdx.x >> 6;         // quarter 0..3
    const int tid = threadIdx.x;

    __shared__ __align__(16) float z[H_];
    __shared__ __align__(16) float zs[H_];
    __shared__ __align__(16) float kb[6][H_];
    __shared__ __align__(16) float a0s[W_];
    __shared__ __align__(16) float a1s[W_];
    __shared__ __align__(16) float red[8][W_];
    __shared__ __align__(16) float4 red4[NB][256];
    __shared__ float gsum[192];
    __shared__ float gaux[ZPB];
    __shared__ float xb[S_ + XC_];
    __shared__ __align__(16) float dxs[XC_];

    int  epoch = 0;
    bool dead  = false;

    // Owner threads write v to LDS dst row + global exchange slot (relaxed agent).
    auto publish = [&](float v, int il, float* dst) {
        dst[q * ZPB + il] = v;
        __hip_atomic_store(&kx[(((size_t)b * 2 + (epoch & 1)) * NB + q) * ZPB + il], v,
                           __ATOMIC_RELAXED, __HIP_MEMORY_SCOPE_AGENT);
    };

    // Barrier among the 4 blocks of this batch, then gather peers' rows into dst.
    // RELAXED-only: no cache maintenance -> L2-resident weights survive.
    auto exchange = [&](float* dst) {
        __syncthreads();   // drains vmcnt(0): publish stores complete at coherence pt
        if (tid == 0)
            __hip_atomic_store(&seq[(b * NB + q) * 16], (unsigned)epoch,
                               __ATOMIC_RELAXED, __HIP_MEMORY_SCOPE_AGENT);
        asm volatile("" ::: "memory");   // compile-time: keep store before polls
        if (tid < NB && tid != q && !dead) {
            unsigned* sp = &seq[(b * NB + tid) * 16];
            int guard = 0;
            while (__hip_atomic_load(sp, __ATOMIC_RELAXED,
                                     __HIP_MEMORY_SCOPE_AGENT) < (unsigned)epoch) {
                __builtin_amdgcn_s_sleep(2);
                if (++guard > (1 << 22)) { dead = true; break; }
            }
        }
        __syncthreads();
        if (tid < H_) {
            int qq = tid >> 6, ii = tid & 63;
            if (qq != q)
                dst[tid] = __hip_atomic_load(
                    &kx[(((size_t)b * 2 + (epoch & 1)) * NB + qq) * ZPB + ii],
                    __ATOMIC_RELAXED, __HIP_MEMORY_SCOPE_AGENT);
        }
        __syncthreads();
    };

    // ---------------- Encoder: 100 GRU steps, gate rows distributed ----------
    const int   seg = tid >> 6;          // 0=reset,1=update,2=new (tid<192)
    const int   l63 = tid & 63;
    const int   gr  = seg * H_ + q * ZPB + l63;
    const float gbr = (tid < 192) ? gru_b[gr] : 0.f;
    const float bnr = (tid < ZPB) ? gru_bn[q * ZPB + tid] : 0.f;

    if (tid < H_) z[tid] = 0.f;
    __syncthreads();

    for (int step = 0; step < L_IN; ++step) {
        if (tid < S_ + XC_) {
            float v;
            if (tid < S_)                v = y_past[(b * L_IN + step) * S_ + tid];
            else if (tid < S_ + XC_ - 1) v = cx[(b * T_ + step) * (XC_ - 1) + (tid - S_)];
            else                         v = tvals[step];
            xb[tid] = v;
        }
        __syncthreads();
        if (tid < 192) {
            float ig = gbr;
            #pragma unroll
            for (int k = 0; k < S_ + XC_; ++k) ig += wihT[k * GR_ + gr] * xb[k];
            float hg = 0.f, hg2 = 0.f;
            #pragma unroll 8
            for (int k = 0; k < H_; k += 2) {
                hg  += whhT[k * GR_ + gr]       * z[k];
                hg2 += whhT[(k + 1) * GR_ + gr] * z[k + 1];
            }
            hg += hg2;
            if (seg < 2) gsum[tid] = ig + hg;
            else { gsum[tid] = ig; gaux[l63] = hg; }
        }
        __syncthreads();
        epoch++;
        if (tid < ZPB) {
            float rr = sigmoid_f(gsum[tid]);
            float uu = sigmoid_f(gsum[64 + tid]);
            float nn = tanhf(gsum[128 + tid] + rr * (gaux[tid] + bnr));
            float zo = z[q * ZPB + tid];
            publish(nn + uu * (zo - nn), tid, z);
        }
        exchange(z);
    }

    // readout (block q==0 only)
    auto readout = [&](int idx) {
        if (q == 0 && tid < 8 * 64) {
            int o  = tid >> 6;
            int kk = tid & 63;
            float4 wv = reinterpret_cast<const float4*>(ro_w)[o * 64 + kk];
            float4 zv = *reinterpret_cast<const float4*>(&z[kk * 4]);
            float p = wv.x * zv.x + wv.y * zv.y + wv.z * zv.z + wv.w * zv.w;
            p += __shfl_xor(p, 1);
            p += __shfl_xor(p, 2);
            p += __shfl_xor(p, 4);
            p += __shfl_xor(p, 8);
            p += __shfl_xor(p, 16);
            p += __shfl_xor(p, 32);
            if (kk == 0) out[(b * L_IN + idx) * O_ + o] = p + ro_b[o];
        }
    };

    readout(0);

    // ---------------- Register-resident weights for the ODE phase ------------
    const int r  = tid & 127;      // MLP output row (a0/a1 stages)
    const int g  = tid >> 7;       // split-K group 0..7 (a0/a1 stages)
    const int g2 = tid >> 8;       // W2 k-group 0..3
    const int u  = tid & 255;      // W2 row-quad index

    // W0/W1 rows are contiguous per thread in the ORIGINAL row-major layout.
    float4 w0r[8];
    {
        const float4* w04 = reinterpret_cast<const float4*>(w0);
        #pragma unroll
        for (int c = 0; c < 8; ++c) w0r[c] = w04[r * 64 + g * 8 + c];
    }
    float4 w1r[4];
    {
        const float4* w14 = reinterpret_cast<const float4*>(w1);
        #pragma unroll
        for (int c = 0; c < 4; ++c) w1r[c] = w14[r * 32 + g * 4 + c];
    }
    const float4* __restrict__ w2T4 = reinterpret_cast<const float4*>(w2T);
    float4 w2c[W2REG];
    #pragma unroll
    for (int j = 0; j < W2REG; ++j)
        w2c[j] = w2T4[(size_t)(g2 * 32 + j) * 1024 + q * 256 + u];

    float4 b2c = make_float4(0.f, 0.f, 0.f, 0.f);
    if (tid < 256) b2c = reinterpret_cast<const float4*>(b2)[q * 256 + tid];
    const float b0r = (tid < W_) ? b0[tid] : 0.f;
    const float b1r = (tid < W_) ? b1[tid] : 0.f;
    float4 dx4 = make_float4(0.f, 0.f, 0.f, 0.f);

    // vf: kb[s] = vf(zin, dxdt). Block computes full a0/a1 (replicated across the
    // 4 blocks of the batch), then its own 1024 W2-rows -> 64 k-rows, exchanged.
    auto vf = [&](const float* zin, int s) {
        {   // a0 partial: row r, k in [g*32, g*32+32)
            const float4* z4 = reinterpret_cast<const float4*>(zin) + g * 8;
            float acc0 = 0.f, acc1 = 0.f;
            #pragma unroll
            for (int c = 0; c < 8; ++c) {
                float4 zv = z4[c];
                acc0 += w0r[c].x * zv.x + w0r[c].y * zv.y;
                acc1 += w0r[c].z * zv.z + w0r[c].w * zv.w;
            }
            red[g][r] = acc0 + acc1;
        }
        __syncthreads();
        if (tid < W_) {
            float sa = b0r;
            #pragma unroll
            for (int gg = 0; gg < 8; ++gg) sa += red[gg][tid];
            a0s[tid] = softplus_f(sa);
        }
        __syncthreads();
        {   // a1 partial: row r, k in [g*16, g*16+16)
            const float4* a4 = reinterpret_cast<const float4*>(a0s) + g * 4;
            float acc0 = 0.f, acc1 = 0.f;
            #pragma unroll
            for (int c = 0; c < 4; ++c) {
                float4 av = a4[c];
                acc0 += w1r[c].x * av.x + w1r[c].y * av.y;
                acc1 += w1r[c].z * av.z + w1r[c].w * av.w;
            }
            red[g][r] = acc0 + acc1;
        }
        __syncthreads();
        if (tid < W_) {
            float sa = b1r;
            #pragma unroll
            for (int gg = 0; gg < 8; ++gg) sa += red[gg][tid];
            a1s[tid] = softplus_f(sa);
        }
        __syncthreads();
        {   // W2: thread (g2,u) handles rows q*1024+4u..+3, k in [g2*32, g2*32+32)
            float4 acc = make_float4(0.f, 0.f, 0.f, 0.f);
            #pragma unroll
            for (int j = 0; j < W2REG; ++j) {
                float av = a1s[g2 * 32 + j];
                acc.x += w2c[j].x * av; acc.y += w2c[j].y * av;
                acc.z += w2c[j].z * av; acc.w += w2c[j].w * av;
            }
            const float4* wp = w2T4 + (size_t)(g2 * 32 + W2REG) * 1024 + q * 256 + u;
            #pragma unroll 8
            for (int j = 0; j < 32 - W2REG; ++j) {
                float4 wv = wp[(size_t)j * 1024];
                float av = a1s[g2 * 32 + W2REG + j];
                acc.x += wv.x * av; acc.y += wv.y * av;
                acc.z += wv.z * av; acc.w += wv.w * av;
            }
            red4[g2][u] = acc;
        }
        __syncthreads();
        epoch++;
        if (tid < 256) {
            float4 t0 = red4[0][tid], t1 = red4[1][tid];
            float4 t2 = red4[2][tid], t3 = red4[3][tid];
            float p = tanhf(t0.x + t1.x + t2.x + t3.x + b2c.x) * dx4.x
                    + tanhf(t0.y + t1.y + t2.y + t3.y + b2c.y) * dx4.y
                    + tanhf(t0.z + t1.z + t2.z + t3.z + b2c.z) * dx4.z
                    + tanhf(t0.w + t1.w + t2.w + t3.w + b2c.w) * dx4.w;
            p += __shfl_xor(p, 1);
            p += __shfl_xor(p, 2);
            if ((tid & 3) == 0) publish(p, tid >> 2, &kb[s][0]);
        }
        exchange(&kb[s][0]);
    };

    // ---------------- ODE: 99 intervals x 2 dopri5 substeps ------------------
    for (int i = 0; i < T_ - L_IN - 1; ++i) {
        float dt = tvals[L_IN + i + 1] - tvals[L_IN + i];
        if (tid < XC_) {
            float xa, xbv;
            if (tid < XC_ - 1) {
                xa  = cx[(b * T_ + L_IN + i) * (XC_ - 1) + tid];
                xbv = cx[(b * T_ + L_IN + i + 1) * (XC_ - 1) + tid];
            } else {
                xa  = tvals[L_IN + i];
                xbv = tvals[L_IN + i + 1];
            }
            dxs[tid] = (xbv - xa) / dt;
        }
        const float hh = dt * 0.5f;   // N_SUB = 2
        __syncthreads();
        if (tid < 256) dx4 = reinterpret_cast<const float4*>(dxs)[tid & 3];

        for (int sub = 0; sub < 2; ++sub) {
            vf(z, 0);
            if (tid < H_) zs[tid] = z[tid] + hh * (0.2f * kb[0][tid]);
            __syncthreads();
            vf(zs, 1);
            if (tid < H_) zs[tid] = z[tid] + hh * (0.075f * kb[0][tid] + 0.225f * kb[1][tid]);
            __syncthreads();
            vf(zs, 2);
            if (tid < H_) zs[tid] = z[tid] + hh * ((44.f / 45.f) * kb[0][tid]
                                                - (56.f / 15.f) * kb[1][tid]
                                                + (32.f / 9.f) * kb[2][tid]);
            __syncthreads();
            vf(zs, 3);
            if (tid < H_) zs[tid] = z[tid] + hh * ((19372.f / 6561.f) * kb[0][tid]
                                                - (25360.f / 2187.f) * kb[1][tid]
                                                + (64448.f / 6561.f) * kb[2][tid]
                                                - (212.f / 729.f) * kb[3][tid]);
            __syncthreads();
            vf(zs, 4);
            if (tid < H_) zs[tid] = z[tid] + hh * ((9017.f / 3168.f) * kb[0][tid]
                                                - (355.f / 33.f) * kb[1][tid]
                                                + (46732.f / 5247.f) * kb[2][tid]
                                                + (49.f / 176.f) * kb[3][tid]
                                                - (5103.f / 18656.f) * kb[4][tid]);
            __syncthreads();
            vf(zs, 5);
            if (tid < H_) {
                z[tid] = z[tid] + hh * ((35.f / 384.f) * kb[0][tid]
                                      + (500.f / 1113.f) * kb[2][tid]
                                      + (125.f / 192.f) * kb[3][tid]
                                      - (2187.f / 6784.f) * kb[4][tid]
                                      + (11.f / 84.f) * kb[5][tid]);
            }
            __syncthreads();
        }
        readout(i + 1);
    }
}

// ---------------------------------------------------------------------------
// Fallback (ws too small): monolithic kernel, original weight layouts.
// ---------------------------------------------------------------------------
__global__ __launch_bounds__(NT) void gru_cde_mono(
    const float* __restrict__ y_past, const float* __restrict__ tvals,
    const float* __restrict__ cx,
    const float* __restrict__ wih, const float* __restrict__ whh,
    const float* __restrict__ gru_b, const float* __restrict__ gru_bn,
    const float* __restrict__ w0, const float* __restrict__ b0,
    const float* __restrict__ w1, const float* __restrict__ b1,
    const float* __restrict__ w2, const float* __restrict__ b2,
    const float* __restrict__ ro_w, const float* __restrict__ ro_b,
    float* __restrict__ out)
{
    const int b   = blockIdx.x;
    const int tid = threadIdx.x;

    __shared__ __align__(16) float z[H_];
    __shared__ float zs[H_];
    __shared__ float kb[6][H_];
    __shared__ float a0s[W_];
    __shared__ float a1s[W_];
    __shared__ float red[8][W_];
    __shared__ float gsum[GR_];
    __shared__ float gaux[H_];
    __shared__ float xb[S_ + XC_];
    __shared__ float dxs[XC_];

    const float gb_t = (tid < GR_) ? gru_b[tid] : 0.f;
    const float bn_t = (tid < H_) ? gru_bn[tid] : 0.f;
    const float4 bb = reinterpret_cast<const float4*>(b2)[tid];

    if (tid < H_) z[tid] = 0.f;
    __syncthreads();

    for (int step = 0; step < L_IN; ++step) {
        if (tid < S_ + XC_) {
            float v;
            if (tid < S_)                v = y_past[(b * L_IN + step) * S_ + tid];
            else if (tid < S_ + XC_ - 1) v = cx[(b * T_ + step) * (XC_ - 1) + (tid - S_)];
            else                         v = tvals[step];
            xb[tid] = v;
        }
        __syncthreads();
        if (tid < GR_) {
            float ig = gb_t;
            #pragma unroll
            for (int k = 0; k < S_ + XC_; ++k) ig += wih[tid * (S_ + XC_) + k] * xb[k];
            float hg = 0.f;
            #pragma unroll 8
            for (int k = 0; k < H_; ++k) hg += whh[tid * H_ + k] * z[k];
            if (tid < 2 * H_) gsum[tid] = ig + hg;
            else { gsum[tid] = ig; gaux[tid - 2 * H_] = hg; }
        }
        __syncthreads();
        if (tid < H_) {
            float r = sigmoid_f(gsum[tid]);
            float u = sigmoid_f(gsum[tid + H_]);
            float n = tanhf(gsum[tid + 2 * H_] + r * (gaux[tid] + bn_t));
            z[tid] = n + u * (z[tid] - n);
        }
        __syncthreads();
    }

    auto readout = [&](int idx) {
        if (tid < 8 * 64) {
            int o  = tid >> 6;
            int kk = tid & 63;
            float4 wv = reinterpret_cast<const float4*>(ro_w)[o * 64 + kk];
            float4 zv = *reinterpret_cast<const float4*>(&z[kk * 4]);
            float p = wv.x * zv.x + wv.y * zv.y + wv.z * zv.z + wv.w * zv.w;
            p += __shfl_xor(p, 1);
            p += __shfl_xor(p, 2);
            p += __shfl_xor(p, 4);
            p += __shfl_xor(p, 8);
            p += __shfl_xor(p, 16);
            p += __shfl_xor(p, 32);
            if (kk == 0) out[(b * L_IN + idx) * O_ + o] = p + ro_b[o];
        }
    };

    readout(0);

    auto vf = [&](const float* zin, int s) {
        const int g = tid >> 7;
        const int r = tid & 127;
        {
            float acc = 0.f;
            const int k0 = g * 32;
            #pragma unroll 8
            for (int k = k0; k < k0 + 32; ++k) acc += w0[r * H_ + k] * zin[k];
            red[g][r] = acc;
        }
        __syncthreads();
        if (tid < W_) {
            float sa = b0[tid];
            #pragma unroll
            for (int gg = 0; gg < 8; ++gg) sa += red[gg][tid];
            a0s[tid] = softplus_f(sa);
        }
        __syncthreads();
        {
            float acc = 0.f;
            const int k0 = g * 16;
            #pragma unroll
            for (int k = k0; k < k0 + 16; ++k) acc += w1[r * W_ + k] * a0s[k];
            red[g][r] = acc;
        }
        __syncthreads();
        if (tid < W_) {
            float sa = b1[tid];
            #pragma unroll
            for (int gg = 0; gg < 8; ++gg) sa += red[gg][tid];
            a1s[tid] = softplus_f(sa);
        }
        __syncthreads();
        {
            float4 acc = make_float4(0.f, 0.f, 0.f, 0.f);
            const int jj = tid * 4;
            #pragma unroll 4
            for (int k = 0; k < W_; ++k) {
                float av = a1s[k];
                acc.x += w2[(jj + 0) * W_ + k] * av;
                acc.y += w2[(jj + 1) * W_ + k] * av;
                acc.z += w2[(jj + 2) * W_ + k] * av;
                acc.w += w2[(jj + 3) * W_ + k] * av;
            }
            const int c0 = jj & 15;
            float p = tanhf(acc.x + bb.x) * dxs[c0]
                    + tanhf(acc.y + bb.y) * dxs[c0 + 1]
                    + tanhf(acc.z + bb.z) * dxs[c0 + 2]
                    + tanhf(acc.w + bb.w) * dxs[c0 + 3];
            p += __shfl_xor(p, 1);
            p += __shfl_xor(p, 2);
            if ((tid & 3) == 0) kb[s][tid >> 2] = p;
        }
        __syncthreads();
    };

    for (int i = 0; i < T_ - L_IN - 1; ++i) {
        float dt = tvals[L_IN + i + 1] - tvals[L_IN + i];
        if (tid < XC_) {
            float xa, xbv;
            if (tid < XC_ - 1) {
                xa  = cx[(b * T_ + L_IN + i) * (XC_ - 1) + tid];
                xbv = cx[(b * T_ + L_IN + i + 1) * (XC_ - 1) + tid];
            } else {
                xa  = tvals[L_IN + i];
                xbv = tvals[L_IN + i + 1];
            }
            dxs[tid] = (xbv - xa) / dt;
        }
        const float hh = dt * 0.5f;
        __syncthreads();

        for (int sub = 0; sub < 2; ++sub) {
            vf(z, 0);
            if (tid < H_) zs[tid] = z[tid] + hh * (0.2f * kb[0][tid]);
            __syncthreads();
            vf(zs, 1);
            if (tid < H_) zs[tid] = z[tid] + hh * (0.075f * kb[0][tid] + 0.225f * kb[1][tid]);
            __syncthreads();
            vf(zs, 2);
            if (tid < H_) zs[tid] = z[tid] + hh * ((44.f / 45.f) * kb[0][tid]
                                                - (56.f / 15.f) * kb[1][tid]
                                                + (32.f / 9.f) * kb[2][tid]);
            __syncthreads();
            vf(zs, 3);
            if (tid < H_) zs[tid] = z[tid] + hh * ((19372.f / 6561.f) * kb[0][tid]
                                                - (25360.f / 2187.f) * kb[1][tid]
                                                + (64448.f / 6561.f) * kb[2][tid]
                                                - (212.f / 729.f) * kb[3][tid]);
            __syncthreads();
            vf(zs, 4);
            if (tid < H_) zs[tid] = z[tid] + hh * ((9017.f / 3168.f) * kb[0][tid]
                                                - (355.f / 33.f) * kb[1][tid]
                                                + (46732.f / 5247.f) * kb[2][tid]
                                                + (49.f / 176.f) * kb[3][tid]
                                                - (5103.f / 18656.f) * kb[4][tid]);
            __syncthreads();
            vf(zs, 5);
            if (tid < H_) {
                z[tid] = z[tid] + hh * ((35.f / 384.f) * kb[0][tid]
                                      + (500.f / 1113.f) * kb[2][tid]
                                      + (125.f / 192.f) * kb[3][tid]
                                      - (2187.f / 6784.f) * kb[4][tid]
                                      + (11.f / 84.f) * kb[5][tid]);
            }
            __syncthreads();
        }
        readout(i + 1);
    }
}

extern "C" void kernel_launch(void* const* d_in, const int* in_sizes, int n_in,
                              void* d_out, int out_size, void* d_ws, size_t ws_size,
                              hipStream_t stream) {
    const float* y_past = (const float*)d_in[0];
    const float* tvals  = (const float*)d_in[1];
    const float* cx     = (const float*)d_in[2];
    const float* wih    = (const float*)d_in[3];
    const float* whh    = (const float*)d_in[4];
    const float* gb     = (const float*)d_in[5];
    const float* gbn    = (const float*)d_in[6];
    const float* w0     = (const float*)d_in[7];
    const float* b0     = (const float*)d_in[8];
    const float* w1     = (const float*)d_in[9];
    const float* b1     = (const float*)d_in[10];
    const float* w2     = (const float*)d_in[11];
    const float* b2     = (const float*)d_in[12];
    const float* ro_w   = (const float*)d_in[13];
    const float* ro_b   = (const float*)d_in[14];
    float* out = (float*)d_out;

    if (ws_size >= WS_FLOATS * sizeof(float)) {
        float* ws = (float*)d_ws;
        auto launchT = [&](const float* in, float* o, int R, int K) {
            int n = R * K;
            transpose_kernel<<<(n + 255) / 256, 256, 0, stream>>>(in, o, R, K);
        };
        launchT(wih, ws + OFF_WIHT, GR_, S_ + XC_);
        launchT(whh, ws + OFF_WHHT, GR_, H_);
        launchT(w2,  ws + OFF_W2T,  HXC, W_);
        int nseq = B_ * NB * 16;
        init_seq_kernel<<<(nseq + 255) / 256, 256, 0, stream>>>(
            (unsigned*)(ws + OFF_SEQ), nseq);
        gru_cde_dist<<<B_ * NB, NT, 0, stream>>>(
            y_past, tvals, cx,
            ws + OFF_WIHT, ws + OFF_WHHT, gb, gbn,
            w0, b0, w1, b1, ws + OFF_W2T, b2,
            ro_w, ro_b, ws + OFF_KX, (unsigned*)(ws + OFF_SEQ), out);
    } else {
        gru_cde_mono<<<B_, NT, 0, stream>>>(
            y_past, tvals, cx,
            wih, whh, gb, gbn,
            w0, b0, w1, b1, w2, b2,
            ro_w, ro_b, out);
    }
}